// Round 2
// baseline (675.023 us; speedup 1.0000x reference)
//
#include <hip/hip_runtime.h>
#include <hip/hip_bf16.h>
#include <stdint.h>

#define BATCH 8192
#define IN_F  4096
#define OUT_F 4096

#define BM 128
#define BN 128
#define BK 64

typedef __attribute__((ext_vector_type(8))) short bf16x8;   // 8 bf16 = 4 VGPRs
typedef __attribute__((ext_vector_type(4))) float f32x4;

// ---------- helpers ----------

__device__ __forceinline__ unsigned short f2bf(float f) {
    // round-to-nearest-even bf16 (inputs are finite; no NaN handling needed)
    unsigned int u = __float_as_uint(f);
    unsigned int lsb = (u >> 16) & 1u;
    u += 0x7fffu + lsb;
    return (unsigned short)(u >> 16);
}

__device__ __forceinline__ void gl_lds16(const void* g, void* l) {
    // async global->LDS, 16B per lane. HW dest = wave-uniform base + lane*16.
    __builtin_amdgcn_global_load_lds(
        (const __attribute__((address_space(1))) void*)g,
        (__attribute__((address_space(3))) void*)l,
        16, 0, 0);
}

// ---------- convert kernels ----------

// x: [BATCH, IN_F] fp32 -> bf16, 8 elems/thread
__global__ __launch_bounds__(256) void cvt_x_kernel(const float4* __restrict__ x,
                                                    uint4* __restrict__ o) {
    int i = blockIdx.x * 256 + threadIdx.x;
    float4 a = x[2 * i];
    float4 b = x[2 * i + 1];
    union { unsigned short u[8]; uint4 v; } r;
    r.u[0] = f2bf(a.x); r.u[1] = f2bf(a.y); r.u[2] = f2bf(a.z); r.u[3] = f2bf(a.w);
    r.u[4] = f2bf(b.x); r.u[5] = f2bf(b.y); r.u[6] = f2bf(b.z); r.u[7] = f2bf(b.w);
    o[i] = r.v;
}

// wm = weight*mask: [OUT_F, IN_F] fp32 -> bf16, 8 elems/thread
__global__ __launch_bounds__(256) void cvt_w_kernel(const float4* __restrict__ w,
                                                    const float4* __restrict__ m,
                                                    uint4* __restrict__ o) {
    int i = blockIdx.x * 256 + threadIdx.x;
    float4 wa = w[2 * i], wb = w[2 * i + 1];
    float4 ma = m[2 * i], mb = m[2 * i + 1];
    union { unsigned short u[8]; uint4 v; } r;
    r.u[0] = f2bf(wa.x * ma.x); r.u[1] = f2bf(wa.y * ma.y);
    r.u[2] = f2bf(wa.z * ma.z); r.u[3] = f2bf(wa.w * ma.w);
    r.u[4] = f2bf(wb.x * mb.x); r.u[5] = f2bf(wb.y * mb.y);
    r.u[6] = f2bf(wb.z * mb.z); r.u[7] = f2bf(wb.w * mb.w);
    o[i] = r.v;
}

// ---------- GEMM: C[M,N] = A[M,K] * W[N,K]^T + bias ----------
// m97 structure: 128x128 tile, BK=64, 4 waves (2x2), 4x4 accs of 16x16x32 MFMA,
// global_load_lds width=16 staging, ds_read_b128 fragment loads with XOR chunk
// swizzle (chunk' = chunk ^ (row&7)) so b128 reads stay at the 8-phase minimum.
__global__ __launch_bounds__(256) void gemm_kernel(const unsigned short* __restrict__ A,
                                                   const unsigned short* __restrict__ W,
                                                   const float* __restrict__ bias,
                                                   float* __restrict__ C) {
    __shared__ unsigned short lA[BM * BK];   // 16 KiB
    __shared__ unsigned short lB[BN * BK];   // 16 KiB

    const int tid  = threadIdx.x;
    const int lane = tid & 63;
    const int wave = tid >> 6;
    const int bm = blockIdx.y;
    const int bn = blockIdx.x;

    const int wm = (wave & 1) * 64;   // wave's row offset in the 128 tile
    const int wn = (wave >> 1) * 64;  // wave's col offset
    const int q  = lane >> 4;         // 0..3
    const int r  = lane & 15;         // 0..15
    const int swz = r & 7;            // rows of a fragment read all have row&7 == r&7

    f32x4 acc[4][4] = {};

    // staging slots: 1024 slots of 16B per tile; slot s -> row = s>>3, stored
    // chunk = s&7, fetched global chunk = (s&7) ^ (row&7)
    const unsigned short* Ab = A + (size_t)(bm * BM) * IN_F;
    const unsigned short* Wb = W + (size_t)(bn * BN) * IN_F;

    int rowS[4], cgS[4], ldsoff[4];
#pragma unroll
    for (int i = 0; i < 4; ++i) {
        int s = i * 256 + tid;
        rowS[i] = s >> 3;
        cgS[i]  = (s & 7) ^ (rowS[i] & 7);
        ldsoff[i] = s * 8;            // in elements (16B per slot)
    }

    for (int kt = 0; kt < IN_F; kt += BK) {
#pragma unroll
        for (int i = 0; i < 4; ++i) {
            gl_lds16(Ab + (size_t)rowS[i] * IN_F + kt + cgS[i] * 8, &lA[ldsoff[i]]);
            gl_lds16(Wb + (size_t)rowS[i] * IN_F + kt + cgS[i] * 8, &lB[ldsoff[i]]);
        }
        __syncthreads();   // drains vmcnt (global_load_lds) + barrier

#pragma unroll
        for (int ks = 0; ks < 2; ++ks) {
            bf16x8 af[4], bfj[4];
            const int c = ((ks * 4 + q) ^ swz) * 8;
#pragma unroll
            for (int i = 0; i < 4; ++i) {
                int row = wm + i * 16 + r;
                af[i] = *(const bf16x8*)&lA[row * BK + c];
            }
#pragma unroll
            for (int j = 0; j < 4; ++j) {
                int row = wn + j * 16 + r;
                bfj[j] = *(const bf16x8*)&lB[row * BK + c];
            }
#pragma unroll
            for (int i = 0; i < 4; ++i)
#pragma unroll
                for (int j = 0; j < 4; ++j)
                    acc[i][j] = __builtin_amdgcn_mfma_f32_16x16x32_bf16(
                        af[i], bfj[j], acc[i][j], 0, 0, 0);
        }
        __syncthreads();
    }

    // epilogue: C/D layout col = lane&15, row = (lane>>4)*4 + reg
    const int crow0 = bm * BM + wm;
    const int ccol0 = bn * BN + wn;
#pragma unroll
    for (int j = 0; j < 4; ++j) {
        const int col = ccol0 + j * 16 + r;
        const float bj = bias[col];
#pragma unroll
        for (int i = 0; i < 4; ++i) {
#pragma unroll
            for (int t = 0; t < 4; ++t) {
                int row = crow0 + i * 16 + q * 4 + t;
                C[(size_t)row * OUT_F + col] = acc[i][j][t] + bj;
            }
        }
    }
}

// ---------- fallback (no workspace): correct-but-slow fp32 path ----------
// Only used if ws_size is too small for the bf16 staging buffers, so we never
// write out of bounds of d_ws.
__global__ __launch_bounds__(256) void fallback_kernel(const float* __restrict__ x,
                                                       const float* __restrict__ w,
                                                       const float* __restrict__ bias,
                                                       const float* __restrict__ m,
                                                       float* __restrict__ out) {
    size_t idx = (size_t)blockIdx.x * 256 + threadIdx.x;   // over BATCH*OUT_F
    int row = (int)(idx >> 12);        // / OUT_F
    int col = (int)(idx & (OUT_F - 1));
    const float4* xr = (const float4*)(x + (size_t)row * IN_F);
    const float4* wr = (const float4*)(w + (size_t)col * IN_F);
    const float4* mr = (const float4*)(m + (size_t)col * IN_F);
    float s = 0.f;
    for (int k = 0; k < IN_F / 4; ++k) {
        float4 xv = xr[k], wv = wr[k], mv = mr[k];
        s += xv.x * wv.x * mv.x + xv.y * wv.y * mv.y +
             xv.z * wv.z * mv.z + xv.w * wv.w * mv.w;
    }
    out[idx] = s + bias[col];
}

// ---------- launch ----------

extern "C" void kernel_launch(void* const* d_in, const int* in_sizes, int n_in,
                              void* d_out, int out_size, void* d_ws, size_t ws_size,
                              hipStream_t stream) {
    const float* x    = (const float*)d_in[0];
    const float* w    = (const float*)d_in[1];
    const float* bias = (const float*)d_in[2];
    const float* mask = (const float*)d_in[3];
    float* out = (float*)d_out;

    const size_t need = ((size_t)BATCH * IN_F + (size_t)OUT_F * IN_F) * sizeof(unsigned short);
    if (ws_size < need) {
        // workspace too small for bf16 staging — safe, slow fp32 path
        fallback_kernel<<<(size_t)BATCH * OUT_F / 256, 256, 0, stream>>>(
            x, w, bias, mask, out);
        return;
    }

    // workspace layout: x_bf16 [BATCH*IN_F] then w_bf16 [OUT_F*IN_F]
    unsigned short* xb = (unsigned short*)d_ws;
    unsigned short* wb = xb + (size_t)BATCH * IN_F;

    cvt_x_kernel<<<(BATCH * IN_F) / 8 / 256, 256, 0, stream>>>(
        (const float4*)x, (uint4*)xb);
    cvt_w_kernel<<<(OUT_F * IN_F) / 8 / 256, 256, 0, stream>>>(
        (const float4*)w, (const float4*)mask, (uint4*)wb);

    dim3 grid(OUT_F / BN, BATCH / BM);   // 32 x 64 = 2048 blocks
    gemm_kernel<<<grid, 256, 0, stream>>>(xb, wb, bias, out);
}

// Round 3
// 590.084 us; speedup vs baseline: 1.1439x; 1.1439x over previous
//
#include <hip/hip_runtime.h>
#include <hip/hip_bf16.h>
#include <stdint.h>

#define BATCH 8192
#define IN_F  4096
#define OUT_F 4096

#define BM 128
#define BN 128
#define BK 64

typedef __attribute__((ext_vector_type(8)))  short bf16x8;   // 8 bf16 = 4 VGPRs
typedef __attribute__((ext_vector_type(16))) float f32x16;   // 32x32 MFMA acc

// ---------- helpers ----------

__device__ __forceinline__ unsigned short f2bf(float f) {
    // round-to-nearest-even bf16 (inputs are finite; no NaN handling needed)
    unsigned int u = __float_as_uint(f);
    unsigned int lsb = (u >> 16) & 1u;
    u += 0x7fffu + lsb;
    return (unsigned short)(u >> 16);
}

__device__ __forceinline__ void gl_lds16(const void* g, void* l) {
    // async global->LDS, 16B per lane. HW dest = wave-uniform base + lane*16.
    __builtin_amdgcn_global_load_lds(
        (const __attribute__((address_space(1))) void*)g,
        (__attribute__((address_space(3))) void*)l,
        16, 0, 0);
}

// ---------- fused convert kernel ----------
// blocks [0, XBLK)        : x fp32 -> bf16            (8 elems/thread)
// blocks [XBLK, XBLK+WBLK): weight*mask fp32 -> bf16  (8 elems/thread)
#define XBLK ((BATCH * IN_F) / 8 / 256)
#define WBLK ((OUT_F * IN_F) / 8 / 256)

__global__ __launch_bounds__(256) void cvt_kernel(const float4* __restrict__ x,
                                                  const float4* __restrict__ w,
                                                  const float4* __restrict__ m,
                                                  uint4* __restrict__ xo,
                                                  uint4* __restrict__ wo) {
    int b = blockIdx.x;
    union { unsigned short u[8]; uint4 v; } r;
    if (b < XBLK) {
        int i = b * 256 + threadIdx.x;
        float4 a0 = x[2 * i], a1 = x[2 * i + 1];
        r.u[0] = f2bf(a0.x); r.u[1] = f2bf(a0.y); r.u[2] = f2bf(a0.z); r.u[3] = f2bf(a0.w);
        r.u[4] = f2bf(a1.x); r.u[5] = f2bf(a1.y); r.u[6] = f2bf(a1.z); r.u[7] = f2bf(a1.w);
        xo[i] = r.v;
    } else {
        int i = (b - XBLK) * 256 + threadIdx.x;
        float4 wa = w[2 * i], wb = w[2 * i + 1];
        float4 ma = m[2 * i], mb = m[2 * i + 1];
        r.u[0] = f2bf(wa.x * ma.x); r.u[1] = f2bf(wa.y * ma.y);
        r.u[2] = f2bf(wa.z * ma.z); r.u[3] = f2bf(wa.w * ma.w);
        r.u[4] = f2bf(wb.x * mb.x); r.u[5] = f2bf(wb.y * mb.y);
        r.u[6] = f2bf(wb.z * mb.z); r.u[7] = f2bf(wb.w * mb.w);
        wo[i] = r.v;
    }
}

// ---------- GEMM: C[M,N] = A[M,K] * W[N,K]^T + bias ----------
// 128x128 tile, BK=64, 4 waves (2x2), each wave: 2x2 accs of 32x32x16 MFMA.
// global_load_lds width=16 staging; ds_read_b128 fragment loads with XOR chunk
// swizzle (stored chunk = chunk ^ (row&7)) -> 8-phase minimum, conflict-free.
// 32x32 shape: half the MFMA instructions of 16x16 path, +15% pipe rate (m119),
// and frag regs drop 32->16 VGPRs so launch_bounds(256,4) fits 4 blocks/CU.
__global__ __launch_bounds__(256, 4) void gemm_kernel(const unsigned short* __restrict__ A,
                                                      const unsigned short* __restrict__ W,
                                                      const float* __restrict__ bias,
                                                      float* __restrict__ C) {
    __shared__ unsigned short lA[BM * BK];   // 16 KiB
    __shared__ unsigned short lB[BN * BK];   // 16 KiB

    const int tid  = threadIdx.x;
    const int lane = tid & 63;
    const int wave = tid >> 6;
    const int bm = blockIdx.y;
    const int bn = blockIdx.x;

    const int wm = (wave & 1) * 64;   // wave's row offset in the 128 tile
    const int wn = (wave >> 1) * 64;  // wave's col offset
    const int r32 = lane & 31;
    const int hi  = lane >> 5;        // k-group (0/1)
    const int swz = lane & 7;         // fragment rows all satisfy row&7 == lane&7

    f32x16 acc[2][2] = {};

    const unsigned short* Ab = A + (size_t)(bm * BM) * IN_F;
    const unsigned short* Wb = W + (size_t)(bn * BN) * IN_F;

    // staging slots: 1024 slots of 16B per tile; slot s -> row = s>>3, stored
    // chunk = s&7, fetched global chunk = (s&7) ^ (row&7)
    int rowS[4], cgS[4], ldsoff[4];
#pragma unroll
    for (int i = 0; i < 4; ++i) {
        int s = i * 256 + tid;
        rowS[i] = s >> 3;
        cgS[i]  = (s & 7) ^ (rowS[i] & 7);
        ldsoff[i] = s * 8;            // in elements (16B per slot)
    }

    for (int kt = 0; kt < IN_F; kt += BK) {
#pragma unroll
        for (int i = 0; i < 4; ++i) {
            gl_lds16(Ab + (size_t)rowS[i] * IN_F + kt + cgS[i] * 8, &lA[ldsoff[i]]);
            gl_lds16(Wb + (size_t)rowS[i] * IN_F + kt + cgS[i] * 8, &lB[ldsoff[i]]);
        }
        __syncthreads();   // drains vmcnt (global_load_lds) + barrier

#pragma unroll
        for (int ks = 0; ks < 4; ++ks) {          // 4 k-steps of 16
            const int c = ((ks * 2 + hi) ^ swz) * 8;
            bf16x8 af[2], bfj[2];
#pragma unroll
            for (int i = 0; i < 2; ++i)
                af[i] = *(const bf16x8*)&lA[(wm + i * 32 + r32) * BK + c];
#pragma unroll
            for (int j = 0; j < 2; ++j)
                bfj[j] = *(const bf16x8*)&lB[(wn + j * 32 + r32) * BK + c];
#pragma unroll
            for (int i = 0; i < 2; ++i)
#pragma unroll
                for (int j = 0; j < 2; ++j)
                    acc[i][j] = __builtin_amdgcn_mfma_f32_32x32x16_bf16(
                        af[i], bfj[j], acc[i][j], 0, 0, 0);
        }
        __syncthreads();
    }

    // epilogue: 32x32 C/D layout: col = lane&31, row = (reg&3)+8*(reg>>2)+4*(lane>>5)
    const int crow0 = bm * BM + wm;
    const int ccol0 = bn * BN + wn;
#pragma unroll
    for (int j = 0; j < 2; ++j) {
        const int col = ccol0 + j * 32 + r32;
        const float bj = bias[col];
#pragma unroll
        for (int i = 0; i < 2; ++i) {
#pragma unroll
            for (int reg = 0; reg < 16; ++reg) {
                int row = crow0 + i * 32 + (reg & 3) + 8 * (reg >> 2) + 4 * hi;
                C[(size_t)row * OUT_F + col] = acc[i][j][reg] + bj;
            }
        }
    }
}

// ---------- fallback (no workspace): correct-but-slow fp32 path ----------
__global__ __launch_bounds__(256) void fallback_kernel(const float* __restrict__ x,
                                                       const float* __restrict__ w,
                                                       const float* __restrict__ bias,
                                                       const float* __restrict__ m,
                                                       float* __restrict__ out) {
    size_t idx = (size_t)blockIdx.x * 256 + threadIdx.x;   // over BATCH*OUT_F
    int row = (int)(idx >> 12);        // / OUT_F
    int col = (int)(idx & (OUT_F - 1));
    const float4* xr = (const float4*)(x + (size_t)row * IN_F);
    const float4* wr = (const float4*)(w + (size_t)col * IN_F);
    const float4* mr = (const float4*)(m + (size_t)col * IN_F);
    float s = 0.f;
    for (int k = 0; k < IN_F / 4; ++k) {
        float4 xv = xr[k], wv = wr[k], mv = mr[k];
        s += xv.x * wv.x * mv.x + xv.y * wv.y * mv.y +
             xv.z * wv.z * mv.z + xv.w * wv.w * mv.w;
    }
    out[idx] = s + bias[col];
}

// ---------- launch ----------

extern "C" void kernel_launch(void* const* d_in, const int* in_sizes, int n_in,
                              void* d_out, int out_size, void* d_ws, size_t ws_size,
                              hipStream_t stream) {
    const float* x    = (const float*)d_in[0];
    const float* w    = (const float*)d_in[1];
    const float* bias = (const float*)d_in[2];
    const float* mask = (const float*)d_in[3];
    float* out = (float*)d_out;

    const size_t need = ((size_t)BATCH * IN_F + (size_t)OUT_F * IN_F) * sizeof(unsigned short);
    if (ws_size < need) {
        fallback_kernel<<<(size_t)BATCH * OUT_F / 256, 256, 0, stream>>>(
            x, w, bias, mask, out);
        return;
    }

    // workspace layout: x_bf16 [BATCH*IN_F] then w_bf16 [OUT_F*IN_F]
    unsigned short* xb = (unsigned short*)d_ws;
    unsigned short* wb = xb + (size_t)BATCH * IN_F;

    cvt_kernel<<<XBLK + WBLK, 256, 0, stream>>>(
        (const float4*)x, (const float4*)w, (const float4*)mask,
        (uint4*)xb, (uint4*)wb);

    dim3 grid(OUT_F / BN, BATCH / BM);   // 32 x 64 = 2048 blocks
    gemm_kernel<<<grid, 256, 0, stream>>>(xb, wb, bias, out);
}